// Round 15
// baseline (2189.114 us; speedup 1.0000x reference)
//
#include <hip/hip_runtime.h>
#include <math.h>

#define N_   4096
#define E_   128
#define H_   256
#define G4_  1024
#define SCALE_T 2.8853900817779268f   // 2*log2(e): exp2(S*x) = e^(2x)
#define L2E_    1.4426950408889634f   // log2(e)
#define NEG_BIG -1.0e30f              // finite stand-in for -inf
#define NSWEEP_ 24                    // Jacobi sweeps per phase (rho^24 ~ 5e-6)
#define PFIN_   0                     // final parity after an even number of sweeps

typedef _Float16 half8 __attribute__((ext_vector_type(8)));
typedef float    f32x4 __attribute__((ext_vector_type(4)));
typedef unsigned uvec4 __attribute__((ext_vector_type(4)));

__device__ __forceinline__ float sigm_fast(float x) {
    return __builtin_amdgcn_rcpf(1.f + __builtin_amdgcn_exp2f(-L2E_ * x));
}
__device__ __forceinline__ float tanh_fast(float x) {
    return 1.f - 2.f * __builtin_amdgcn_rcpf(1.f + __builtin_amdgcn_exp2f(SCALE_T * x));
}

// ---------------------------------------------------------------------------
// init: pos[i]=INF, tour tail of d_out
// ---------------------------------------------------------------------------
__global__ __launch_bounds__(256) void init_misc(
    const int* __restrict__ tour, float* __restrict__ out_tail, int* __restrict__ pos)
{
    const int i = blockIdx.x * 256 + threadIdx.x;
    if (i < N_) {
        pos[i] = 0x7FFFFFFF;
        out_tail[i] = (float)tour[i];
    }
}

__global__ __launch_bounds__(256) void pos_scatter(
    const int* __restrict__ tour, int* __restrict__ pos)
{
    const int i = blockIdx.x * 256 + threadIdx.x;
    if (i < N_) atomicMin(&pos[tour[i]], i);
}

// ---------------------------------------------------------------------------
// embeddings
// ---------------------------------------------------------------------------
__global__ __launch_bounds__(256) void embed2(
    const float* __restrict__ x,
    const float* __restrict__ eW, const float* __restrict__ eb,
    const float* __restrict__ cW, const float* __restrict__ cb,
    float* __restrict__ emb, float* __restrict__ city)
{
    const int m = blockIdx.x, tid = threadIdx.x;
    const float x0 = x[2*m], x1 = x[2*m+1];
    if (tid < E_) {
        emb[(size_t)m*E_ + tid] = x0*eW[2*tid] + x1*eW[2*tid+1] + eb[tid];
    } else {
        const int e = tid - E_;
        city[(size_t)m*E_ + e] = x0*cW[2*e] + x1*cW[2*e+1] + cb[e];
    }
}

__global__ __launch_bounds__(128) void gather_dec(
    const float* __restrict__ city, const float* __restrict__ st,
    const int* __restrict__ tour, float* __restrict__ dseq)
{
    const int t = blockIdx.x, e = threadIdx.x;
    dseq[(size_t)t*E_ + e] = (t == 0) ? st[e] : city[(size_t)tour[t-1]*E_ + e];
}

// ---------------------------------------------------------------------------
// generic fp32 GEMM: C[M,N] = scale*(A[M,K] @ B[N,K]^T) (+b0) (+b1)
// storeT / out16 / act(tanh) epilogue options
// ---------------------------------------------------------------------------
__global__ __launch_bounds__(256) void gemm64(
    const float* __restrict__ A, const float* __restrict__ B, void* __restrict__ Cv,
    int M, int N, int K, const float* __restrict__ b0, const float* __restrict__ b1,
    float scale, int storeT, int out16, int act)
{
    __shared__ float As[16][68];
    __shared__ float Bs[16][68];
    const int tid = threadIdx.x;
    const int m0 = blockIdx.y * 64, n0 = blockIdx.x * 64;
    const int tx = tid & 15, ty = tid >> 4;
    const int lr = tid >> 2, lk = (tid & 3) * 4;
    float acc[4][4] = {};
    for (int kb = 0; kb < K; kb += 16) {
        const float4 a4 = *(const float4*)&A[(size_t)(m0+lr)*K + kb + lk];
        const float4 b4 = *(const float4*)&B[(size_t)(n0+lr)*K + kb + lk];
        __syncthreads();
        As[lk][lr]=a4.x; As[lk+1][lr]=a4.y; As[lk+2][lr]=a4.z; As[lk+3][lr]=a4.w;
        Bs[lk][lr]=b4.x; Bs[lk+1][lr]=b4.y; Bs[lk+2][lr]=b4.z; Bs[lk+3][lr]=b4.w;
        __syncthreads();
        #pragma unroll
        for (int k = 0; k < 16; ++k) {
            const float4 av4 = *(const float4*)&As[k][ty*4];
            const float4 bv4 = *(const float4*)&Bs[k][tx*4];
            const float avv[4] = {av4.x, av4.y, av4.z, av4.w};
            const float bvv[4] = {bv4.x, bv4.y, bv4.z, bv4.w};
            #pragma unroll
            for (int i = 0; i < 4; ++i)
                #pragma unroll
                for (int j = 0; j < 4; ++j)
                    acc[i][j] += avv[i] * bvv[j];
        }
    }
    #pragma unroll
    for (int i = 0; i < 4; ++i) {
        const int m = m0 + ty*4 + i;
        #pragma unroll
        for (int j = 0; j < 4; ++j) {
            const int n = n0 + tx*4 + j;
            float val = scale * acc[i][j];
            if (b0) val += b0[n];
            if (b1) val += b1[n];
            if (act) val = tanh_fast(val);
            const size_t idx = storeT ? ((size_t)n*M + m) : ((size_t)m*N + n);
            if (out16) ((_Float16*)Cv)[idx] = (_Float16)val;
            else       ((float*)Cv)[idx] = val;
        }
    }
}

// ---------------------------------------------------------------------------
// Jacobi LSTM solver. R15: M-tile 64, 512 threads (8 waves), 64 blocks.
// Per-block B read (0.5 MB) amortized over 4x rows; inner loop 12 loads ->
// 32 MFMA per k-step. Wave w owns 32 h-cols (c0=w*32) x 4 gates x 4 row-tiles.
// ---------------------------------------------------------------------------
__global__ __launch_bounds__(256) void wcvt(
    const float* __restrict__ we, const float* __restrict__ wd,
    _Float16* __restrict__ we16, _Float16* __restrict__ wd16)
{
    const int i = blockIdx.x * 256 + threadIdx.x;
    we16[i] = (_Float16)we[i];
    wd16[i] = (_Float16)wd[i];
}

__global__ __launch_bounds__(256) void zero4(uvec4* __restrict__ p, long n4)
{
    const uvec4 z = (uvec4){0u, 0u, 0u, 0u};
    for (long i = blockIdx.x * 256 + threadIdx.x; i < n4; i += (long)gridDim.x * 256)
        p[i] = z;
}

__global__ __launch_bounds__(256) void extract_fin(
    const _Float16* __restrict__ Hb, const float* __restrict__ Cb,
    float* __restrict__ stash)
{
    const int l = threadIdx.x;
    stash[l]       = (float)Hb[(size_t)PFIN_*(4097*H_) + (size_t)N_*H_ + l];
    stash[256 + l] = Cb[(size_t)PFIN_*(4097*H_) + (size_t)N_*H_ + l];
}

__global__ __launch_bounds__(256) void seed0(
    const float* __restrict__ stash, _Float16* __restrict__ Hb, float* __restrict__ Cb)
{
    const int l = threadIdx.x;
    const _Float16 h = (_Float16)stash[l];
    const float    c = stash[256 + l];
    Hb[l] = h; Hb[(size_t)(4097*H_) + l] = h;
    Cb[l] = c; Cb[(size_t)(4097*H_) + l] = c;
}

// fused sweep v2: 64 blocks x 512 thr; block rows [row0, row0+64)
__global__ __launch_bounds__(512, 1) void sweep_fused2(
    const _Float16* __restrict__ A, const _Float16* __restrict__ B,
    const _Float16* __restrict__ xih,
    const float* __restrict__ Cin, float* __restrict__ Cout,
    _Float16* __restrict__ Hout)
{
    const int lane = threadIdx.x & 63, w = threadIdx.x >> 6;   // 8 waves
    const int row0 = blockIdx.x * 64;
    const int ra = lane & 15, kg = lane >> 4;
    f32x4 acc[4][4][2] = {};   // [row-tile][gate][col-sub16]
    #pragma unroll
    for (int kb = 0; kb < 256; kb += 32) {
        const int ko = kb + kg * 8;
        half8 a[4];
        #pragma unroll
        for (int rt = 0; rt < 4; ++rt)
            a[rt] = *(const half8*)&A[(size_t)(row0 + rt*16 + ra)*H_ + ko];
        #pragma unroll
        for (int gq = 0; gq < 4; ++gq)
            #pragma unroll
            for (int cs = 0; cs < 2; ++cs) {
                const int bcol = gq*256 + w*32 + cs*16;
                const half8 b = *(const half8*)&B[(size_t)(bcol + ra)*H_ + ko];
                #pragma unroll
                for (int rt = 0; rt < 4; ++rt)
                    acc[rt][gq][cs] = __builtin_amdgcn_mfma_f32_16x16x32_f16(
                        a[rt], b, acc[rt][gq][cs], 0, 0, 0);
            }
    }
    // in-register cell update; acc row=kg*4+r, col=cs*16+ra (within wave chunk)
    #pragma unroll
    for (int rt = 0; rt < 4; ++rt)
        #pragma unroll
        for (int cs = 0; cs < 2; ++cs)
            #pragma unroll
            for (int r = 0; r < 4; ++r) {
                const int row = row0 + rt*16 + kg*4 + r;   // sequence position s
                const int col = w*32 + cs*16 + ra;         // h element
                const size_t xb = (size_t)row*G4_ + col;
                const float gi = acc[rt][0][cs][r] + (float)xih[xb      ];
                const float gf = acc[rt][1][cs][r] + (float)xih[xb + 256];
                const float gg = acc[rt][2][cs][r] + (float)xih[xb + 512];
                const float go = acc[rt][3][cs][r] + (float)xih[xb + 768];
                const float iv = sigm_fast(gi);
                const float fv = sigm_fast(gf);
                const float gv = tanh_fast(gg);
                const float ov = sigm_fast(go);
                const float cn = fv * Cin[(size_t)row*H_ + col] + iv * gv;
                const float hn = ov * tanh_fast(cn);
                Cout[(size_t)(row + 1)*H_ + col] = cn;
                Hout[(size_t)(row + 1)*H_ + col] = (_Float16)hn;
            }
}

__global__ __launch_bounds__(256) void cvt_H(
    const _Float16* __restrict__ Hb, float* __restrict__ hfin)
{
    const int s = blockIdx.x, l = threadIdx.x;
    hfin[(size_t)s*H_ + l] = (float)Hb[(size_t)(s+1)*H_ + l];
}

// ---------------------------------------------------------------------------
// attention via Taylor-split GEMM (R14, unchanged):
//   e[t][i] = Pv[i] + Uv[t] - (1/256) * <[16*v*tp^2 ; 16*tp], [16*tu ; 16*v*tu^2]>
// ---------------------------------------------------------------------------
__global__ __launch_bounds__(256) void prep_side(
    const float* __restrict__ tmat, const float* __restrict__ v,
    _Float16* __restrict__ A16, float* __restrict__ rv)
{
    const int row = blockIdx.x, tid = threadIdx.x;
    const float t = tmat[(size_t)row*H_ + tid];
    const float vv = v[tid];
    A16[(size_t)row*512 + tid]       = (_Float16)(16.f * vv * t * t);
    A16[(size_t)row*512 + 256 + tid] = (_Float16)(16.f * t);
    __shared__ float red[256];
    red[tid] = vv * t;
    __syncthreads();
    for (int s = 128; s > 0; s >>= 1) {
        if (tid < s) red[tid] += red[tid + s];
        __syncthreads();
    }
    if (tid == 0) rv[row] = red[0];
}

__global__ __launch_bounds__(256) void attn_mm(
    const _Float16* __restrict__ Bt, const _Float16* __restrict__ Ai,
    const float* __restrict__ Uv, const float* __restrict__ Pv,
    const int* __restrict__ pos, float* __restrict__ out)
{
    const int lane = threadIdx.x & 63, w = threadIdx.x >> 6;
    const int t0 = blockIdx.y * 64, i0 = blockIdx.x * 64;
    const int pi = pos[i0 + lane];
    if (__all(pi < t0)) return;               // whole tile masked; logsm2 fills
    const int m0 = t0 + w*16;
    const int ra = lane & 15, kg = lane >> 4;
    f32x4 acc[4] = {};
    #pragma unroll
    for (int kb = 0; kb < 512; kb += 32) {
        const int ko = kb + kg * 8;
        const half8 a = *(const half8*)&Bt[(size_t)(m0 + ra)*512 + ko];
        #pragma unroll
        for (int nt = 0; nt < 4; ++nt) {
            const half8 b = *(const half8*)&Ai[(size_t)(i0 + nt*16 + ra)*512 + ko];
            acc[nt] = __builtin_amdgcn_mfma_f32_16x16x32_f16(a, b, acc[nt], 0, 0, 0);
        }
    }
    #pragma unroll
    for (int r = 0; r < 4; ++r) {
        const int t = m0 + kg*4 + r;
        const float uv = Uv[t];
        #pragma unroll
        for (int nt = 0; nt < 4; ++nt) {
            const int i = i0 + nt*16 + ra;
            out[(size_t)t*N_ + i] = uv + Pv[i] - acc[nt][r] * (1.f/256.f);
        }
    }
}

__global__ __launch_bounds__(256) void logsm2(
    const int* __restrict__ pos, float* __restrict__ out)
{
    const int t = blockIdx.x, tid = threadIdx.x;
    float* row = out + (size_t)t*N_;
    float v[16];
    float lmax = NEG_BIG;
    #pragma unroll
    for (int j = 0; j < 16; ++j) {
        const int i = tid + j*256;
        const float rv = row[i];               // finite garbage if masked
        v[j] = (pos[i] < t) ? NEG_BIG : rv;
        lmax = fmaxf(lmax, v[j]);
    }
    __shared__ float red[256];
    red[tid] = lmax; __syncthreads();
    for (int s = 128; s > 0; s >>= 1) {
        if (tid < s) red[tid] = fmaxf(red[tid], red[tid + s]);
        __syncthreads();
    }
    const float m = red[0];
    __syncthreads();
    float lsum = 0.f;
    #pragma unroll
    for (int j = 0; j < 16; ++j) lsum += __expf(v[j] - m);
    red[tid] = lsum; __syncthreads();
    for (int s = 128; s > 0; s >>= 1) {
        if (tid < s) red[tid] += red[tid + s];
        __syncthreads();
    }
    const float lse = m + logf(red[0]);
    #pragma unroll
    for (int j = 0; j < 16; ++j) row[tid + j*256] = v[j] - lse;
}

// ---------------------------------------------------------------------------
extern "C" void kernel_launch(void* const* d_in, const int* in_sizes, int n_in,
                              void* d_out, int out_size, void* d_ws, size_t ws_size,
                              hipStream_t stream)
{
    const float* x        = (const float*)d_in[0];
    const int*   tour     = (const int*)  d_in[1];
    const float* eW       = (const float*)d_in[2];
    const float* eb       = (const float*)d_in[3];
    const float* enc_Wih  = (const float*)d_in[4];
    const float* enc_Whh  = (const float*)d_in[5];
    const float* enc_bih  = (const float*)d_in[6];
    const float* enc_bhh  = (const float*)d_in[7];
    const float* dec_Wih  = (const float*)d_in[8];
    const float* dec_Whh  = (const float*)d_in[9];
    const float* dec_bih  = (const float*)d_in[10];
    const float* dec_bhh  = (const float*)d_in[11];
    const float* W1       = (const float*)d_in[12];
    const float* W2       = (const float*)d_in[13];
    const float* attv     = (const float*)d_in[14];
    const float* cW       = (const float*)d_in[15];
    const float* cb       = (const float*)d_in[16];
    const float* st       = (const float*)d_in[17];
    float* out = (float*)d_out;

    float* ws = (float*)d_ws;
    size_t o = 0;
    float* emb    = ws + o; o += (size_t)N_*E_;
    float* city   = ws + o; o += (size_t)N_*E_;
    float* dseq   = ws + o; o += (size_t)N_*E_;
    float* tpmat  = ws + o; o += (size_t)N_*H_;   // tanh(W1 @ enc_out) [i][d]
    float* tumat  = ws + o; o += (size_t)N_*H_;   // tanh(W2 @ hx)      [t][d]
    float* hfin   = ws + o; o += (size_t)N_*H_;
    float* Pv     = ws + o; o += N_;
    float* Uv     = ws + o; o += N_;
    float* stash  = ws + o; o += 512;
    int*   pos    = (int*)(ws + o); o += N_;
    float* Cb     = ws + o; o += (size_t)2*4097*H_;
    _Float16* xih_e = (_Float16*)(ws + o); o += (size_t)N_*G4_/2;
    _Float16* xih_d = (_Float16*)(ws + o); o += (size_t)N_*G4_/2;
    _Float16* Hb    = (_Float16*)(ws + o); o += (size_t)2*4097*H_/2;
    _Float16* we16  = (_Float16*)(ws + o); o += (size_t)G4_*H_/2;
    _Float16* wd16  = (_Float16*)(ws + o); o += (size_t)G4_*H_/2;
    _Float16* A16i  = (_Float16*)(ws + o); o += (size_t)N_*512/2;   // i-side factors
    _Float16* B16t  = (_Float16*)(ws + o); o += (size_t)N_*512/2;   // t-side factors

    const size_t HP = (size_t)4097*H_;
    const size_t CP = (size_t)4097*H_;
    const long  h4 = (long)(2*HP*2/16);
    const long  c4 = (long)(2*CP*4/16);

    init_misc  <<<16, 256, 0, stream>>>(tour, out + (size_t)N_*N_, pos);
    pos_scatter<<<16, 256, 0, stream>>>(tour, pos);
    embed2     <<<N_, 256, 0, stream>>>(x, eW, eb, cW, cb, emb, city);
    gather_dec <<<N_, 128, 0, stream>>>(city, st, tour, dseq);
    gemm64<<<dim3(G4_/64, N_/64), 256, 0, stream>>>(emb,  enc_Wih, xih_e, N_, G4_, E_, enc_bih, enc_bhh, 1.f, 0, 1, 0);
    gemm64<<<dim3(G4_/64, N_/64), 256, 0, stream>>>(dseq, dec_Wih, xih_d, N_, G4_, E_, dec_bih, dec_bhh, 1.f, 0, 1, 0);
    wcvt  <<<G4_*H_/256, 256, 0, stream>>>(enc_Whh, dec_Whh, we16, wd16);

    // ---- encoder: 24 fused Jacobi sweeps ----
    zero4<<<768, 256, 0, stream>>>((uvec4*)Hb, h4);
    zero4<<<768, 256, 0, stream>>>((uvec4*)Cb, c4);
    for (int m = 0; m < NSWEEP_; ++m) {
        const int p = m & 1;
        sweep_fused2<<<N_/64, 512, 0, stream>>>(Hb + p*HP, we16, xih_e,
                                                Cb + p*CP, Cb + (p^1)*CP, Hb + (p^1)*HP);
    }
    cvt_H <<<N_, 256, 0, stream>>>(Hb + PFIN_*HP, hfin);
    gemm64<<<dim3(H_/64, N_/64), 256, 0, stream>>>(hfin, W1, tpmat, N_, H_, H_, nullptr, nullptr, 1.f, 0, 0, 1);

    // ---- decoder: seed with enc final state, 24 fused sweeps ----
    extract_fin<<<1, 256, 0, stream>>>(Hb, Cb, stash);
    zero4<<<768, 256, 0, stream>>>((uvec4*)Hb, h4);
    zero4<<<768, 256, 0, stream>>>((uvec4*)Cb, c4);
    seed0<<<1, 256, 0, stream>>>(stash, Hb, Cb);
    for (int m = 0; m < NSWEEP_; ++m) {
        const int p = m & 1;
        sweep_fused2<<<N_/64, 512, 0, stream>>>(Hb + p*HP, wd16, xih_d,
                                                Cb + p*CP, Cb + (p^1)*CP, Hb + (p^1)*HP);
    }
    cvt_H <<<N_, 256, 0, stream>>>(Hb + PFIN_*HP, hfin);
    gemm64<<<dim3(H_/64, N_/64), 256, 0, stream>>>(hfin, W2, tumat, N_, H_, H_, nullptr, nullptr, 1.f, 0, 0, 1);

    // ---- attention: factor build + MFMA GEMM + masked log-softmax ----
    prep_side<<<N_, 256, 0, stream>>>(tpmat, attv, A16i, Pv);
    prep_side<<<N_, 256, 0, stream>>>(tumat, attv, B16t, Uv);
    attn_mm  <<<dim3(N_/64, N_/64), 256, 0, stream>>>(B16t, A16i, Uv, Pv, pos, out);
    logsm2   <<<N_, 256, 0, stream>>>(pos, out);
}

// Round 16
// 1208.774 us; speedup vs baseline: 1.8110x; 1.8110x over previous
//
#include <hip/hip_runtime.h>
#include <math.h>

#define N_   4096
#define E_   128
#define H_   256
#define G4_  1024
#define SCALE_T 2.8853900817779268f   // 2*log2(e): exp2(S*x) = e^(2x)
#define L2E_    1.4426950408889634f   // log2(e)
#define NEG_BIG -1.0e30f              // finite stand-in for -inf
#define NSWEEP_ 24                    // Jacobi sweeps per phase (rho^24 ~ 5e-6)
#define PFIN_   0                     // final parity after an even number of sweeps

typedef _Float16 half8 __attribute__((ext_vector_type(8)));
typedef float    f32x4 __attribute__((ext_vector_type(4)));
typedef unsigned uvec4 __attribute__((ext_vector_type(4)));

__device__ __forceinline__ float sigm_fast(float x) {
    return __builtin_amdgcn_rcpf(1.f + __builtin_amdgcn_exp2f(-L2E_ * x));
}
__device__ __forceinline__ float tanh_fast(float x) {
    return 1.f - 2.f * __builtin_amdgcn_rcpf(1.f + __builtin_amdgcn_exp2f(SCALE_T * x));
}

// ---------------------------------------------------------------------------
// init: pos[i]=INF, tour tail of d_out
// ---------------------------------------------------------------------------
__global__ __launch_bounds__(256) void init_misc(
    const int* __restrict__ tour, float* __restrict__ out_tail, int* __restrict__ pos)
{
    const int i = blockIdx.x * 256 + threadIdx.x;
    if (i < N_) {
        pos[i] = 0x7FFFFFFF;
        out_tail[i] = (float)tour[i];
    }
}

__global__ __launch_bounds__(256) void pos_scatter(
    const int* __restrict__ tour, int* __restrict__ pos)
{
    const int i = blockIdx.x * 256 + threadIdx.x;
    if (i < N_) atomicMin(&pos[tour[i]], i);
}

// ---------------------------------------------------------------------------
// embeddings
// ---------------------------------------------------------------------------
__global__ __launch_bounds__(256) void embed2(
    const float* __restrict__ x,
    const float* __restrict__ eW, const float* __restrict__ eb,
    const float* __restrict__ cW, const float* __restrict__ cb,
    float* __restrict__ emb, float* __restrict__ city)
{
    const int m = blockIdx.x, tid = threadIdx.x;
    const float x0 = x[2*m], x1 = x[2*m+1];
    if (tid < E_) {
        emb[(size_t)m*E_ + tid] = x0*eW[2*tid] + x1*eW[2*tid+1] + eb[tid];
    } else {
        const int e = tid - E_;
        city[(size_t)m*E_ + e] = x0*cW[2*e] + x1*cW[2*e+1] + cb[e];
    }
}

__global__ __launch_bounds__(128) void gather_dec(
    const float* __restrict__ city, const float* __restrict__ st,
    const int* __restrict__ tour, float* __restrict__ dseq)
{
    const int t = blockIdx.x, e = threadIdx.x;
    dseq[(size_t)t*E_ + e] = (t == 0) ? st[e] : city[(size_t)tour[t-1]*E_ + e];
}

// ---------------------------------------------------------------------------
// generic fp32 GEMM: C[M,N] = scale*(A[M,K] @ B[N,K]^T) (+b0) (+b1)
// storeT / out16 / act(tanh) epilogue options
// ---------------------------------------------------------------------------
__global__ __launch_bounds__(256) void gemm64(
    const float* __restrict__ A, const float* __restrict__ B, void* __restrict__ Cv,
    int M, int N, int K, const float* __restrict__ b0, const float* __restrict__ b1,
    float scale, int storeT, int out16, int act)
{
    __shared__ float As[16][68];
    __shared__ float Bs[16][68];
    const int tid = threadIdx.x;
    const int m0 = blockIdx.y * 64, n0 = blockIdx.x * 64;
    const int tx = tid & 15, ty = tid >> 4;
    const int lr = tid >> 2, lk = (tid & 3) * 4;
    float acc[4][4] = {};
    for (int kb = 0; kb < K; kb += 16) {
        const float4 a4 = *(const float4*)&A[(size_t)(m0+lr)*K + kb + lk];
        const float4 b4 = *(const float4*)&B[(size_t)(n0+lr)*K + kb + lk];
        __syncthreads();
        As[lk][lr]=a4.x; As[lk+1][lr]=a4.y; As[lk+2][lr]=a4.z; As[lk+3][lr]=a4.w;
        Bs[lk][lr]=b4.x; Bs[lk+1][lr]=b4.y; Bs[lk+2][lr]=b4.z; Bs[lk+3][lr]=b4.w;
        __syncthreads();
        #pragma unroll
        for (int k = 0; k < 16; ++k) {
            const float4 av4 = *(const float4*)&As[k][ty*4];
            const float4 bv4 = *(const float4*)&Bs[k][tx*4];
            const float avv[4] = {av4.x, av4.y, av4.z, av4.w};
            const float bvv[4] = {bv4.x, bv4.y, bv4.z, bv4.w};
            #pragma unroll
            for (int i = 0; i < 4; ++i)
                #pragma unroll
                for (int j = 0; j < 4; ++j)
                    acc[i][j] += avv[i] * bvv[j];
        }
    }
    #pragma unroll
    for (int i = 0; i < 4; ++i) {
        const int m = m0 + ty*4 + i;
        #pragma unroll
        for (int j = 0; j < 4; ++j) {
            const int n = n0 + tx*4 + j;
            float val = scale * acc[i][j];
            if (b0) val += b0[n];
            if (b1) val += b1[n];
            if (act) val = tanh_fast(val);
            const size_t idx = storeT ? ((size_t)n*M + m) : ((size_t)m*N + n);
            if (out16) ((_Float16*)Cv)[idx] = (_Float16)val;
            else       ((float*)Cv)[idx] = val;
        }
    }
}

// ---------------------------------------------------------------------------
// Jacobi LSTM solver. R16: partition BOTH rows and cols (cell update is
// elementwise in col): block (ct,rt) = rows [rt*64,+64) x cols [ct*64,+64).
// Grid 4x64 = 256 blocks (full chip; R15's 64-block grid left 75% idle).
// Wave w owns 16 cols; per k-step: 8 loads -> 16 MFMA; acc = 64 VGPR.
// ---------------------------------------------------------------------------
__global__ __launch_bounds__(256) void wcvt(
    const float* __restrict__ we, const float* __restrict__ wd,
    _Float16* __restrict__ we16, _Float16* __restrict__ wd16)
{
    const int i = blockIdx.x * 256 + threadIdx.x;
    we16[i] = (_Float16)we[i];
    wd16[i] = (_Float16)wd[i];
}

__global__ __launch_bounds__(256) void zero4(uvec4* __restrict__ p, long n4)
{
    const uvec4 z = (uvec4){0u, 0u, 0u, 0u};
    for (long i = blockIdx.x * 256 + threadIdx.x; i < n4; i += (long)gridDim.x * 256)
        p[i] = z;
}

__global__ __launch_bounds__(256) void extract_fin(
    const _Float16* __restrict__ Hb, const float* __restrict__ Cb,
    float* __restrict__ stash)
{
    const int l = threadIdx.x;
    stash[l]       = (float)Hb[(size_t)PFIN_*(4097*H_) + (size_t)N_*H_ + l];
    stash[256 + l] = Cb[(size_t)PFIN_*(4097*H_) + (size_t)N_*H_ + l];
}

__global__ __launch_bounds__(256) void seed0(
    const float* __restrict__ stash, _Float16* __restrict__ Hb, float* __restrict__ Cb)
{
    const int l = threadIdx.x;
    const _Float16 h = (_Float16)stash[l];
    const float    c = stash[256 + l];
    Hb[l] = h; Hb[(size_t)(4097*H_) + l] = h;
    Cb[l] = c; Cb[(size_t)(4097*H_) + l] = c;
}

// fused sweep v3: grid (4 col-tiles, 64 row-tiles) x 256 thr
__global__ __launch_bounds__(256) void sweep_fused3(
    const _Float16* __restrict__ A, const _Float16* __restrict__ B,
    const _Float16* __restrict__ xih,
    const float* __restrict__ Cin, float* __restrict__ Cout,
    _Float16* __restrict__ Hout)
{
    const int lane = threadIdx.x & 63, w = threadIdx.x >> 6;
    const int row0 = blockIdx.y * 64;
    const int col0 = blockIdx.x * 64 + w * 16;     // wave's 16 h-cols
    const int ra = lane & 15, kg = lane >> 4;
    f32x4 acc[4][4] = {};   // [row-tile][gate]
    #pragma unroll
    for (int kb = 0; kb < 256; kb += 32) {
        const int ko = kb + kg * 8;
        half8 a[4];
        #pragma unroll
        for (int rt = 0; rt < 4; ++rt)
            a[rt] = *(const half8*)&A[(size_t)(row0 + rt*16 + ra)*H_ + ko];
        #pragma unroll
        for (int gq = 0; gq < 4; ++gq) {
            const half8 b = *(const half8*)&B[(size_t)(gq*256 + col0 + ra)*H_ + ko];
            #pragma unroll
            for (int rt = 0; rt < 4; ++rt)
                acc[rt][gq] = __builtin_amdgcn_mfma_f32_16x16x32_f16(
                    a[rt], b, acc[rt][gq], 0, 0, 0);
        }
    }
    // in-register cell update; acc row=kg*4+r, col=ra (within wave's 16 cols)
    #pragma unroll
    for (int rt = 0; rt < 4; ++rt)
        #pragma unroll
        for (int r = 0; r < 4; ++r) {
            const int row = row0 + rt*16 + kg*4 + r;   // sequence position s
            const int col = col0 + ra;                 // h element
            const size_t xb = (size_t)row*G4_ + col;
            const float gi = acc[rt][0][r] + (float)xih[xb      ];
            const float gf = acc[rt][1][r] + (float)xih[xb + 256];
            const float gg = acc[rt][2][r] + (float)xih[xb + 512];
            const float go = acc[rt][3][r] + (float)xih[xb + 768];
            const float iv = sigm_fast(gi);
            const float fv = sigm_fast(gf);
            const float gv = tanh_fast(gg);
            const float ov = sigm_fast(go);
            const float cn = fv * Cin[(size_t)row*H_ + col] + iv * gv;
            const float hn = ov * tanh_fast(cn);
            Cout[(size_t)(row + 1)*H_ + col] = cn;
            Hout[(size_t)(row + 1)*H_ + col] = (_Float16)hn;
        }
}

__global__ __launch_bounds__(256) void cvt_H(
    const _Float16* __restrict__ Hb, float* __restrict__ hfin)
{
    const int s = blockIdx.x, l = threadIdx.x;
    hfin[(size_t)s*H_ + l] = (float)Hb[(size_t)(s+1)*H_ + l];
}

// ---------------------------------------------------------------------------
// attention via Taylor-split GEMM (R14, unchanged):
//   e[t][i] = Pv[i] + Uv[t] - (1/256) * <[16*v*tp^2 ; 16*tp], [16*tu ; 16*v*tu^2]>
// ---------------------------------------------------------------------------
__global__ __launch_bounds__(256) void prep_side(
    const float* __restrict__ tmat, const float* __restrict__ v,
    _Float16* __restrict__ A16, float* __restrict__ rv)
{
    const int row = blockIdx.x, tid = threadIdx.x;
    const float t = tmat[(size_t)row*H_ + tid];
    const float vv = v[tid];
    A16[(size_t)row*512 + tid]       = (_Float16)(16.f * vv * t * t);
    A16[(size_t)row*512 + 256 + tid] = (_Float16)(16.f * t);
    __shared__ float red[256];
    red[tid] = vv * t;
    __syncthreads();
    for (int s = 128; s > 0; s >>= 1) {
        if (tid < s) red[tid] += red[tid + s];
        __syncthreads();
    }
    if (tid == 0) rv[row] = red[0];
}

__global__ __launch_bounds__(256) void attn_mm(
    const _Float16* __restrict__ Bt, const _Float16* __restrict__ Ai,
    const float* __restrict__ Uv, const float* __restrict__ Pv,
    const int* __restrict__ pos, float* __restrict__ out)
{
    const int lane = threadIdx.x & 63, w = threadIdx.x >> 6;
    const int t0 = blockIdx.y * 64, i0 = blockIdx.x * 64;
    const int pi = pos[i0 + lane];
    if (__all(pi < t0)) return;               // whole tile masked; logsm2 fills
    const int m0 = t0 + w*16;
    const int ra = lane & 15, kg = lane >> 4;
    f32x4 acc[4] = {};
    #pragma unroll
    for (int kb = 0; kb < 512; kb += 32) {
        const int ko = kb + kg * 8;
        const half8 a = *(const half8*)&Bt[(size_t)(m0 + ra)*512 + ko];
        #pragma unroll
        for (int nt = 0; nt < 4; ++nt) {
            const half8 b = *(const half8*)&Ai[(size_t)(i0 + nt*16 + ra)*512 + ko];
            acc[nt] = __builtin_amdgcn_mfma_f32_16x16x32_f16(a, b, acc[nt], 0, 0, 0);
        }
    }
    #pragma unroll
    for (int r = 0; r < 4; ++r) {
        const int t = m0 + kg*4 + r;
        const float uv = Uv[t];
        #pragma unroll
        for (int nt = 0; nt < 4; ++nt) {
            const int i = i0 + nt*16 + ra;
            out[(size_t)t*N_ + i] = uv + Pv[i] - acc[nt][r] * (1.f/256.f);
        }
    }
}

__global__ __launch_bounds__(256) void logsm2(
    const int* __restrict__ pos, float* __restrict__ out)
{
    const int t = blockIdx.x, tid = threadIdx.x;
    float* row = out + (size_t)t*N_;
    float v[16];
    float lmax = NEG_BIG;
    #pragma unroll
    for (int j = 0; j < 16; ++j) {
        const int i = tid + j*256;
        const float rv = row[i];               // finite garbage if masked
        v[j] = (pos[i] < t) ? NEG_BIG : rv;
        lmax = fmaxf(lmax, v[j]);
    }
    __shared__ float red[256];
    red[tid] = lmax; __syncthreads();
    for (int s = 128; s > 0; s >>= 1) {
        if (tid < s) red[tid] = fmaxf(red[tid], red[tid + s]);
        __syncthreads();
    }
    const float m = red[0];
    __syncthreads();
    float lsum = 0.f;
    #pragma unroll
    for (int j = 0; j < 16; ++j) lsum += __expf(v[j] - m);
    red[tid] = lsum; __syncthreads();
    for (int s = 128; s > 0; s >>= 1) {
        if (tid < s) red[tid] += red[tid + s];
        __syncthreads();
    }
    const float lse = m + logf(red[0]);
    #pragma unroll
    for (int j = 0; j < 16; ++j) row[tid + j*256] = v[j] - lse;
}

// ---------------------------------------------------------------------------
extern "C" void kernel_launch(void* const* d_in, const int* in_sizes, int n_in,
                              void* d_out, int out_size, void* d_ws, size_t ws_size,
                              hipStream_t stream)
{
    const float* x        = (const float*)d_in[0];
    const int*   tour     = (const int*)  d_in[1];
    const float* eW       = (const float*)d_in[2];
    const float* eb       = (const float*)d_in[3];
    const float* enc_Wih  = (const float*)d_in[4];
    const float* enc_Whh  = (const float*)d_in[5];
    const float* enc_bih  = (const float*)d_in[6];
    const float* enc_bhh  = (const float*)d_in[7];
    const float* dec_Wih  = (const float*)d_in[8];
    const float* dec_Whh  = (const float*)d_in[9];
    const float* dec_bih  = (const float*)d_in[10];
    const float* dec_bhh  = (const float*)d_in[11];
    const float* W1       = (const float*)d_in[12];
    const float* W2       = (const float*)d_in[13];
    const float* attv     = (const float*)d_in[14];
    const float* cW       = (const float*)d_in[15];
    const float* cb       = (const float*)d_in[16];
    const float* st       = (const float*)d_in[17];
    float* out = (float*)d_out;

    float* ws = (float*)d_ws;
    size_t o = 0;
    float* emb    = ws + o; o += (size_t)N_*E_;
    float* city   = ws + o; o += (size_t)N_*E_;
    float* dseq   = ws + o; o += (size_t)N_*E_;
    float* tpmat  = ws + o; o += (size_t)N_*H_;   // tanh(W1 @ enc_out) [i][d]
    float* tumat  = ws + o; o += (size_t)N_*H_;   // tanh(W2 @ hx)      [t][d]
    float* hfin   = ws + o; o += (size_t)N_*H_;
    float* Pv     = ws + o; o += N_;
    float* Uv     = ws + o; o += N_;
    float* stash  = ws + o; o += 512;
    int*   pos    = (int*)(ws + o); o += N_;
    float* Cb     = ws + o; o += (size_t)2*4097*H_;
    _Float16* xih_e = (_Float16*)(ws + o); o += (size_t)N_*G4_/2;
    _Float16* xih_d = (_Float16*)(ws + o); o += (size_t)N_*G4_/2;
    _Float16* Hb    = (_Float16*)(ws + o); o += (size_t)2*4097*H_/2;
    _Float16* we16  = (_Float16*)(ws + o); o += (size_t)G4_*H_/2;
    _Float16* wd16  = (_Float16*)(ws + o); o += (size_t)G4_*H_/2;
    _Float16* A16i  = (_Float16*)(ws + o); o += (size_t)N_*512/2;   // i-side factors
    _Float16* B16t  = (_Float16*)(ws + o); o += (size_t)N_*512/2;   // t-side factors

    const size_t HP = (size_t)4097*H_;
    const size_t CP = (size_t)4097*H_;
    const long  h4 = (long)(2*HP*2/16);
    const long  c4 = (long)(2*CP*4/16);

    init_misc  <<<16, 256, 0, stream>>>(tour, out + (size_t)N_*N_, pos);
    pos_scatter<<<16, 256, 0, stream>>>(tour, pos);
    embed2     <<<N_, 256, 0, stream>>>(x, eW, eb, cW, cb, emb, city);
    gather_dec <<<N_, 128, 0, stream>>>(city, st, tour, dseq);
    gemm64<<<dim3(G4_/64, N_/64), 256, 0, stream>>>(emb,  enc_Wih, xih_e, N_, G4_, E_, enc_bih, enc_bhh, 1.f, 0, 1, 0);
    gemm64<<<dim3(G4_/64, N_/64), 256, 0, stream>>>(dseq, dec_Wih, xih_d, N_, G4_, E_, dec_bih, dec_bhh, 1.f, 0, 1, 0);
    wcvt  <<<G4_*H_/256, 256, 0, stream>>>(enc_Whh, dec_Whh, we16, wd16);

    // ---- encoder: 24 fused Jacobi sweeps ----
    zero4<<<768, 256, 0, stream>>>((uvec4*)Hb, h4);
    zero4<<<768, 256, 0, stream>>>((uvec4*)Cb, c4);
    for (int m = 0; m < NSWEEP_; ++m) {
        const int p = m & 1;
        sweep_fused3<<<dim3(4, N_/64), 256, 0, stream>>>(Hb + p*HP, we16, xih_e,
                                                         Cb + p*CP, Cb + (p^1)*CP, Hb + (p^1)*HP);
    }
    cvt_H <<<N_, 256, 0, stream>>>(Hb + PFIN_*HP, hfin);
    gemm64<<<dim3(H_/64, N_/64), 256, 0, stream>>>(hfin, W1, tpmat, N_, H_, H_, nullptr, nullptr, 1.f, 0, 0, 1);

    // ---- decoder: seed with enc final state, 24 fused sweeps ----
    extract_fin<<<1, 256, 0, stream>>>(Hb, Cb, stash);
    zero4<<<768, 256, 0, stream>>>((uvec4*)Hb, h4);
    zero4<<<768, 256, 0, stream>>>((uvec4*)Cb, c4);
    seed0<<<1, 256, 0, stream>>>(stash, Hb, Cb);
    for (int m = 0; m < NSWEEP_; ++m) {
        const int p = m & 1;
        sweep_fused3<<<dim3(4, N_/64), 256, 0, stream>>>(Hb + p*HP, wd16, xih_d,
                                                         Cb + p*CP, Cb + (p^1)*CP, Hb + (p^1)*HP);
    }
    cvt_H <<<N_, 256, 0, stream>>>(Hb + PFIN_*HP, hfin);
    gemm64<<<dim3(H_/64, N_/64), 256, 0, stream>>>(hfin, W2, tumat, N_, H_, H_, nullptr, nullptr, 1.f, 0, 0, 1);

    // ---- attention: factor build + MFMA GEMM + masked log-softmax ----
    prep_side<<<N_, 256, 0, stream>>>(tpmat, attv, A16i, Pv);
    prep_side<<<N_, 256, 0, stream>>>(tumat, attv, B16t, Uv);
    attn_mm  <<<dim3(N_/64, N_/64), 256, 0, stream>>>(B16t, A16i, Uv, Pv, pos, out);
    logsm2   <<<N_, 256, 0, stream>>>(pos, out);
}